// Round 10
// baseline (437.663 us; speedup 1.0000x reference)
//
#include <hip/hip_runtime.h>
#include <math.h>

#define TOKENS 16384
#define HID    4096
#define NEXP   64
#define TOPK   8
#define BT     16                // tokens per block
#define NSTEP  (HID / 32)        // 128 K-steps of 32
#define TAU    5e-4f
#define REFINE_BLOCKS 256

typedef short          bf16x8 __attribute__((ext_vector_type(8)));
typedef unsigned short u16x8  __attribute__((ext_vector_type(8)));
typedef float          f32x4  __attribute__((ext_vector_type(4)));

__device__ __forceinline__ unsigned short bf16_rtn(float x) {
    unsigned u = __builtin_bit_cast(unsigned, x);
    u += 0x7FFFu + ((u >> 16) & 1u);
    return (unsigned short)(u >> 16);
}

__device__ __forceinline__ void splitf(float x, unsigned short& h, unsigned short& l) {
    h = bf16_rtn(x);
    float hf = __builtin_bit_cast(float, (unsigned)h << 16);
    l = bf16_rtn(x - hf);
}

// ---------- prep: W fp32 -> bf16 hi/lo (validated), zero flag counter -------
__global__ __launch_bounds__(256) void prep_kernel(
    const float* __restrict__ w,
    unsigned short* __restrict__ whi,
    unsigned short* __restrict__ wlo,
    int* __restrict__ flag_cnt)
{
    if (blockIdx.x == 0 && threadIdx.x == 0) flag_cnt[0] = 0;
    int gid = blockIdx.x * 256 + threadIdx.x;
    const f32x4* wp = (const f32x4*)w;
    f32x4 v0 = wp[gid * 2 + 0];
    f32x4 v1 = wp[gid * 2 + 1];
    u16x8 h8, l8;
    #pragma unroll
    for (int j = 0; j < 8; ++j) {
        float x = (j < 4) ? v0[j] : v1[j - 4];
        unsigned short h, l;
        splitf(x, h, l);
        h8[j] = h; l8[j] = l;
    }
    *(u16x8*)(whi + (size_t)gid * 8) = h8;
    *(u16x8*)(wlo + (size_t)gid * 8) = l8;
}

// ---------- pass 1: barrier-free equal-depth-ring MFMA GEMM + top-8 ---------
// Key fix for the r5-r9 plateau: vmcnt retires IN ORDER, so mixed-depth
// prefetch collapses the pipeline. Here A(HBM) and B(L2) are issued
// TOGETHER at the same 4-step-ahead ring depth -> consume-waits are
// uniformly counted 3 steps back. No LDS, no barriers in the K-loop;
// 4 blocks/CU x 4 waves = 16 waves/CU of independent dataflow.
__global__ __launch_bounds__(256, 4) void moe_gate_pass1(
    const float* __restrict__ hs,
    const unsigned short* __restrict__ whi,
    const unsigned short* __restrict__ wlo,
    float* __restrict__ out_idx_f,
    float* __restrict__ out_gate,
    int* __restrict__ flag_cnt,
    int* __restrict__ flag_list,
    int flag_cap)
{
    __shared__ float lg[BT * 68];            // epilogue logits only (4.4 KB)

    const int tid  = threadIdx.x;
    const int lane = tid & 63;
    const int wv   = tid >> 6;               // expert group 0..3
    const int t0   = blockIdx.x * BT;
    const int r16  = lane & 15;
    const int l4   = lane >> 4;

    // A-frag pointer: row = token r16, k = l4*8 + j (validated layout)
    const float* ap = hs + (size_t)(t0 + r16) * HID + l4 * 8;
    // B-frag pointers: col = wv*16 + r16, same k layout (validated)
    const unsigned short* bhp = whi + (size_t)(wv * 16 + r16) * HID + l4 * 8;
    const unsigned short* blp = wlo + (size_t)(wv * 16 + r16) * HID + l4 * 8;

    f32x4 acc = {0.f, 0.f, 0.f, 0.f};

    f32x4 Ar[4][2];                          // A ring (static idx after unroll)
    u16x8 Bhr[4], Blr[4];                    // B ring

#define ISSUE(S, T) { \
    const f32x4* pa = (const f32x4*)(ap + (size_t)(T) * 32); \
    Ar[S][0] = pa[0]; \
    Ar[S][1] = pa[1]; \
    Bhr[S] = *(const u16x8*)(bhp + (size_t)(T) * 32); \
    Blr[S] = *(const u16x8*)(blp + (size_t)(T) * 32); }

#define CONSUME(S) { \
    bf16x8 fah, fal; \
    _Pragma("unroll") \
    for (int j = 0; j < 8; ++j) { \
        float x = (j < 4) ? Ar[S][0][j] : Ar[S][1][j - 4]; \
        unsigned u  = __builtin_bit_cast(unsigned, x); \
        unsigned rr = u + 0x7FFFu + ((u >> 16) & 1u); \
        float hf = __builtin_bit_cast(float, rr & 0xFFFF0000u); \
        float lf = x - hf; \
        unsigned ul = __builtin_bit_cast(unsigned, lf); \
        fah[j] = (short)(rr >> 16); \
        fal[j] = (short)((ul + 0x7FFFu + ((ul >> 16) & 1u)) >> 16); \
    } \
    bf16x8 bh = __builtin_bit_cast(bf16x8, Bhr[S]); \
    bf16x8 bl = __builtin_bit_cast(bf16x8, Blr[S]); \
    acc = __builtin_amdgcn_mfma_f32_16x16x32_bf16(fah, bh, acc, 0, 0, 0); \
    acc = __builtin_amdgcn_mfma_f32_16x16x32_bf16(fah, bl, acc, 0, 0, 0); \
    acc = __builtin_amdgcn_mfma_f32_16x16x32_bf16(fal, bh, acc, 0, 0, 0); }

    // prologue: 4 steps in flight (A+B together -> uniform queue)
    ISSUE(0, 0) ISSUE(1, 1) ISSUE(2, 2) ISSUE(3, 3)

    #pragma unroll 1
    for (int it = 0; it < NSTEP / 8; ++it) {
        #pragma unroll
        for (int u = 0; u < 8; ++u) {
            CONSUME(u & 3)                       // consume step it*8+u
            int ns = it * 8 + u + 4;             // refill same slot, 4 ahead
            if (ns > NSTEP - 1) ns = NSTEP - 1;  // tail: dup-load last step
            ISSUE(u & 3, ns)
        }
    }

#undef ISSUE
#undef CONSUME

    // ---- epilogue: logits -> LDS [16][68], top-9 + gap + softmax ----
    __syncthreads();
    #pragma unroll
    for (int r = 0; r < 4; ++r)
        lg[(l4 * 4 + r) * 68 + wv * 16 + r16] = acc[r];
    __syncthreads();

    if (tid < BT) {
        const int t = tid;
        float v[9];
        int   id[9];
        #pragma unroll
        for (int j = 0; j < 9; ++j) { v[j] = -INFINITY; id[j] = -1; }
        for (int e = 0; e < NEXP; ++e) {
            float x = lg[t * 68 + e];
            if (x > v[8]) {
                int p = 8;
                while (p > 0 && v[p - 1] < x) {
                    v[p]  = v[p - 1];
                    id[p] = id[p - 1];
                    --p;
                }
                v[p]  = x;
                id[p] = e;
            }
        }
        float g = v[0] - v[1];
        #pragma unroll
        for (int j = 1; j < 8; ++j) g = fminf(g, v[j] - v[j + 1]);

        bool deferred = false;
        if (g < TAU) {
            int slot = atomicAdd(flag_cnt, 1);
            if (slot < flag_cap) {
                flag_list[slot] = t0 + t;
                deferred = true;
            }
        }
        if (!deferred) {
            float m = v[0];
            float ex[TOPK];
            float s = 0.0f;
            #pragma unroll
            for (int j = 0; j < TOPK; ++j) { ex[j] = expf(v[j] - m); s += ex[j]; }
            float inv = 1.0f / s;
            size_t base = (size_t)(t0 + t) * TOPK;
            #pragma unroll
            for (int j = 0; j < TOPK; ++j) {
                out_idx_f[base + j] = (float)id[j];
                out_gate[base + j]  = ex[j] * inv;
            }
        }
    }
}

// ---------- pass 2: fp64 exact recompute, coalesced (validated) -------------
__global__ __launch_bounds__(256) void moe_gate_refine(
    const float* __restrict__ hs,
    const float* __restrict__ w,
    float* __restrict__ out_idx_f,
    float* __restrict__ out_gate,
    const int* __restrict__ flag_cnt,
    const int* __restrict__ flag_list,
    int flag_cap)
{
    __shared__ float  hrow[HID];
    __shared__ double lgw[4][NEXP];
    __shared__ double lgd[NEXP];
    const int tid  = threadIdx.x;
    const int lane = tid & 63;
    const int wv   = tid >> 6;

    int n = flag_cnt[0];
    if (n > flag_cap) n = flag_cap;

    for (int fi = blockIdx.x; fi < n; fi += gridDim.x) {
        const int t = flag_list[fi];
        #pragma unroll
        for (int i = 0; i < 4; ++i)
            ((f32x4*)hrow)[tid + 256 * i] =
                ((const f32x4*)(hs + (size_t)t * HID))[tid + 256 * i];
        __syncthreads();

        for (int e = 0; e < NEXP; ++e) {
            const f32x4* wp = (const f32x4*)(w + (size_t)e * HID);
            double s0 = 0.0, s1 = 0.0, s2 = 0.0, s3 = 0.0;
            #pragma unroll
            for (int i = 0; i < 4; ++i) {
                f32x4 wf = wp[tid + 256 * i];
                f32x4 af = ((const f32x4*)hrow)[tid + 256 * i];
                s0 = fma((double)wf[0], (double)af[0], s0);
                s1 = fma((double)wf[1], (double)af[1], s1);
                s2 = fma((double)wf[2], (double)af[2], s2);
                s3 = fma((double)wf[3], (double)af[3], s3);
            }
            double d = (s0 + s1) + (s2 + s3);
            #pragma unroll
            for (int off = 32; off > 0; off >>= 1)
                d += __shfl_down(d, off, 64);
            if (lane == 0) lgw[wv][e] = d;
        }
        __syncthreads();
        if (tid < NEXP)
            lgd[tid] = (lgw[0][tid] + lgw[1][tid]) + (lgw[2][tid] + lgw[3][tid]);
        __syncthreads();

        if (tid == 0) {
            double v[TOPK];
            int    id[TOPK];
            #pragma unroll
            for (int j = 0; j < TOPK; ++j) { v[j] = -INFINITY; id[j] = -1; }
            for (int e = 0; e < NEXP; ++e) {
                double x = lgd[e];
                if (x > v[TOPK - 1]) {
                    int p = TOPK - 1;
                    while (p > 0 && v[p - 1] < x) {
                        v[p]  = v[p - 1];
                        id[p] = id[p - 1];
                        --p;
                    }
                    v[p]  = x;
                    id[p] = e;
                }
            }
            double m = v[0];
            double ex[TOPK];
            double s = 0.0;
            #pragma unroll
            for (int j = 0; j < TOPK; ++j) { ex[j] = exp(v[j] - m); s += ex[j]; }
            double inv = 1.0 / s;
            size_t base = (size_t)t * TOPK;
            #pragma unroll
            for (int j = 0; j < TOPK; ++j) {
                out_idx_f[base + j] = (float)id[j];
                out_gate[base + j]  = (float)(ex[j] * inv);
            }
        }
        __syncthreads();
    }
}

extern "C" void kernel_launch(void* const* d_in, const int* in_sizes, int n_in,
                              void* d_out, int out_size, void* d_ws, size_t ws_size,
                              hipStream_t stream) {
    const float* hs = (const float*)d_in[0];
    const float* w  = (const float*)d_in[1];
    float* out      = (float*)d_out;
    float* out_idx  = out;
    float* out_gate = out + (size_t)TOKENS * TOPK;

    unsigned short* whi = (unsigned short*)d_ws;
    unsigned short* wlo = whi + (size_t)NEXP * HID;
    int* flag_cnt  = (int*)(wlo + (size_t)NEXP * HID);
    int* flag_list = flag_cnt + 1;
    long flag_cap_l = ((long)ws_size - 2L * NEXP * HID * 2 - 16) / 4;
    int flag_cap = flag_cap_l < 0 ? 0 : (flag_cap_l > TOKENS ? TOKENS : (int)flag_cap_l);

    hipLaunchKernelGGL(prep_kernel, dim3(NEXP * HID / (256 * 8)), dim3(256), 0, stream,
                       w, whi, wlo, flag_cnt);
    hipLaunchKernelGGL(moe_gate_pass1, dim3(TOKENS / BT), dim3(256), 0, stream,
                       hs, whi, wlo, out_idx, out_gate, flag_cnt, flag_list, flag_cap);
    hipLaunchKernelGGL(moe_gate_refine, dim3(REFINE_BLOCKS), dim3(256), 0, stream,
                       hs, w, out_idx, out_gate, flag_cnt, flag_list, flag_cap);
}

// Round 11
// 251.053 us; speedup vs baseline: 1.7433x; 1.7433x over previous
//
#include <hip/hip_runtime.h>
#include <math.h>

#define TOKENS 16384
#define HID    4096
#define NEXP   64
#define TOPK   8
#define BT     128               // tokens per gemm block
#define KSPLIT 4                 // k-slices (separate blocks, partials in ws)
#define KSL    (HID / KSPLIT)    // 1024 k per block
#define BK     128               // k per LDS chunk
#define NCHUNK (KSL / BK)        // 8
#define TAU    5e-4f
#define FLAG_BYTES 65536
#define REFINE_BLOCKS 256

typedef short          bf16x8 __attribute__((ext_vector_type(8)));
typedef unsigned short u16x8  __attribute__((ext_vector_type(8)));
typedef float          f32x4  __attribute__((ext_vector_type(4)));

__device__ __forceinline__ unsigned short bf16_rtn(float x) {
    unsigned u = __builtin_bit_cast(unsigned, x);
    u += 0x7FFFu + ((u >> 16) & 1u);
    return (unsigned short)(u >> 16);
}

__global__ void zero_cnt_kernel(int* cnt) {
    if (threadIdx.x == 0) cnt[0] = 0;
}

// ---------- gemm: 128tok x 64exp x 1024k per block, bf16 3-split MFMA -------
// B (W-slice) staged fp32->hi/lo bf16 into LDS chunks (dbuf, slot^row XOR
// swizzle both sides); A direct-to-reg ping-pong; raw lgkm-only barriers
// (r9-validated) so reg prefetch rides across. Partials -> ws.
__global__ __launch_bounds__(512, 4) void moe_gemm(
    const float* __restrict__ hs,
    const float* __restrict__ w,
    float* __restrict__ part,     // [KSPLIT][Rr][64]
    int tok0, int Rr)
{
    __shared__ __align__(16) char bsm[65536];   // 2 bufs x (Bhi 16K | Blo 16K)

    const int tid  = threadIdx.x;
    const int lane = tid & 63;
    const int wv   = tid >> 6;               // tok-tile 0..7
    const int tokgrp = blockIdx.x >> 2;
    const int ks     = blockIdx.x & 3;
    const int tokR = tokgrp * BT;            // round-local token base
    const int t0   = tok0 + tokR;
    const int k0   = ks * KSL;
    const int r16  = lane & 15;
    const int l4   = lane >> 4;

    // A: lane -> token row r16 (of this wave's 16), k = l4*8 + j
    const float* ap = hs + (size_t)(t0 + wv * 16 + r16) * HID + k0 + l4 * 8;

    // W staging: thread -> exp row tid>>3, 16 k starting (tid&7)*16
    const int sexp = tid >> 3;
    const int sk8  = tid & 7;
    const float* wp = w + (size_t)sexp * HID + k0 + sk8 * 16;
    const int wo0 = sexp * 256 + (((2 * sk8)     ^ (sexp & 15)) << 4);
    const int wo1 = sexp * 256 + (((2 * sk8 + 1) ^ (sexp & 15)) << 4);

    f32x4 acc[4];
    #pragma unroll
    for (int g = 0; g < 4; ++g) { acc[g][0]=0.f; acc[g][1]=0.f; acc[g][2]=0.f; acc[g][3]=0.f; }

    f32x4 Apb[8], Aqb[8];                    // A ping-pong banks (static idx)
    f32x4 Wr[4];                             // W chunk stage (16 floats)

#define ALOAD(BANK, C) { \
    const float* p = ap + (size_t)(C) * BK; \
    _Pragma("unroll") \
    for (int s = 0; s < 4; ++s) { \
        BANK[2*s]   = *(const f32x4*)(p + s * 32); \
        BANK[2*s+1] = *(const f32x4*)(p + s * 32 + 4); } }

#define WLOAD(C) { \
    const float* p = wp + (size_t)(C) * BK; \
    _Pragma("unroll") \
    for (int j = 0; j < 4; ++j) Wr[j] = *(const f32x4*)(p + j * 4); }

#define CONVW(BUFOFF) { \
    u16x8 h8[2], l8[2]; \
    _Pragma("unroll") \
    for (int j = 0; j < 16; ++j) { \
        float x = Wr[j >> 2][j & 3]; \
        unsigned u  = __builtin_bit_cast(unsigned, x); \
        unsigned rr = u + 0x7FFFu + ((u >> 16) & 1u); \
        float hf = __builtin_bit_cast(float, rr & 0xFFFF0000u); \
        float lf = x - hf; \
        unsigned ul = __builtin_bit_cast(unsigned, lf); \
        h8[j >> 3][j & 7] = (unsigned short)(rr >> 16); \
        l8[j >> 3][j & 7] = (unsigned short)((ul + 0x7FFFu + ((ul >> 16) & 1u)) >> 16); \
    } \
    *(u16x8*)(bsm + (BUFOFF) + wo0) = h8[0]; \
    *(u16x8*)(bsm + (BUFOFF) + wo1) = h8[1]; \
    *(u16x8*)(bsm + (BUFOFF) + 16384 + wo0) = l8[0]; \
    *(u16x8*)(bsm + (BUFOFF) + 16384 + wo1) = l8[1]; }

#define COMPUTE(ABANK, BUFOFF) { \
    _Pragma("unroll") \
    for (int s = 0; s < 4; ++s) { \
        bf16x8 fah, fal; \
        _Pragma("unroll") \
        for (int j = 0; j < 8; ++j) { \
            float x = (j < 4) ? ABANK[2*s][j] : ABANK[2*s+1][j - 4]; \
            unsigned u  = __builtin_bit_cast(unsigned, x); \
            unsigned rr = u + 0x7FFFu + ((u >> 16) & 1u); \
            float hf = __builtin_bit_cast(float, rr & 0xFFFF0000u); \
            float lf = x - hf; \
            unsigned ul = __builtin_bit_cast(unsigned, lf); \
            fah[j] = (short)(rr >> 16); \
            fal[j] = (short)((ul + 0x7FFFu + ((ul >> 16) & 1u)) >> 16); \
        } \
        _Pragma("unroll") \
        for (int g = 0; g < 4; ++g) { \
            int off = (g * 16 + r16) * 256 + ((((s * 4 + l4) ^ r16)) << 4); \
            bf16x8 bh = *(const bf16x8*)(bsm + (BUFOFF) + off); \
            bf16x8 bl = *(const bf16x8*)(bsm + (BUFOFF) + 16384 + off); \
            acc[g] = __builtin_amdgcn_mfma_f32_16x16x32_bf16(fah, bh, acc[g], 0, 0, 0); \
            acc[g] = __builtin_amdgcn_mfma_f32_16x16x32_bf16(fah, bl, acc[g], 0, 0, 0); \
            acc[g] = __builtin_amdgcn_mfma_f32_16x16x32_bf16(fal, bh, acc[g], 0, 0, 0); \
        } } }

#define BAR() { asm volatile("s_waitcnt lgkmcnt(0)" ::: "memory"); \
    __builtin_amdgcn_sched_barrier(0); \
    __builtin_amdgcn_s_barrier(); \
    __builtin_amdgcn_sched_barrier(0); }

    // prologue: chunk 0 -> bufP(0), A chunk 0 -> Apb
    WLOAD(0)
    ALOAD(Apb, 0)
    CONVW(0)
    BAR()

    #pragma unroll 1
    for (int c2 = 0; c2 < NCHUNK; c2 += 2) {
        // even chunk c2: compute(Apb, buf0); prefetch c2+1 -> Aqb/buf1
        WLOAD(c2 + 1)
        ALOAD(Aqb, c2 + 1)
        COMPUTE(Apb, 0)
        CONVW(32768)
        BAR()
        // odd chunk c2+1: compute(Aqb, buf1); prefetch c2+2 -> Apb/buf0
        if (c2 + 2 < NCHUNK) {
            WLOAD(c2 + 2)
            ALOAD(Apb, c2 + 2)
            COMPUTE(Aqb, 32768)
            CONVW(0)
        } else {
            COMPUTE(Aqb, 32768)
        }
        BAR()
    }

#undef ALOAD
#undef WLOAD
#undef CONVW
#undef COMPUTE
#undef BAR

    // partial write: token_local = wv*16 + l4*4 + r ; exp = g*16 + r16
    const size_t pbase = ((size_t)ks * Rr + tokR + wv * 16 + l4 * 4) * 64;
    #pragma unroll
    for (int g = 0; g < 4; ++g)
        #pragma unroll
        for (int r = 0; r < 4; ++r)
            part[pbase + (size_t)r * 64 + g * 16 + r16] = acc[g][r];
}

// ---------- finisher: sum 4 partials, top-9 + gap + softmax (validated) -----
__global__ __launch_bounds__(256) void moe_finish(
    const float* __restrict__ part,
    float* __restrict__ out_idx_f,
    float* __restrict__ out_gate,
    int* __restrict__ flag_cnt,
    int* __restrict__ flag_list,
    int flag_cap, int tok0, int Rr)
{
    __shared__ float lg[64 * 65];
    const int tid = threadIdx.x;
    const int T0  = blockIdx.x * 64;         // round-local

    const size_t sl = (size_t)Rr * 64;
    for (int i = tid; i < 64 * 64; i += 256) {
        int tt = i >> 6, e = i & 63;
        size_t idx = (size_t)(T0 + tt) * 64 + e;
        lg[tt * 65 + e] = (part[idx] + part[idx + sl]) +
                          (part[idx + 2 * sl] + part[idx + 3 * sl]);
    }
    __syncthreads();

    if (tid < 64) {
        const int t = tid;
        float v[9];
        int   id[9];
        #pragma unroll
        for (int j = 0; j < 9; ++j) { v[j] = -INFINITY; id[j] = -1; }
        for (int e = 0; e < NEXP; ++e) {
            float x = lg[t * 65 + e];
            if (x > v[8]) {
                int p = 8;
                while (p > 0 && v[p - 1] < x) {
                    v[p]  = v[p - 1];
                    id[p] = id[p - 1];
                    --p;
                }
                v[p]  = x;
                id[p] = e;
            }
        }
        float g = v[0] - v[1];
        #pragma unroll
        for (int j = 1; j < 8; ++j) g = fminf(g, v[j] - v[j + 1]);

        const int gt = tok0 + T0 + t;
        bool deferred = false;
        if (g < TAU) {
            int slot = atomicAdd(flag_cnt, 1);
            if (slot < flag_cap) {
                flag_list[slot] = gt;
                deferred = true;
            }
        }
        if (!deferred) {
            float m = v[0];
            float ex[TOPK];
            float s = 0.0f;
            #pragma unroll
            for (int j = 0; j < TOPK; ++j) { ex[j] = expf(v[j] - m); s += ex[j]; }
            float inv = 1.0f / s;
            size_t base = (size_t)gt * TOPK;
            #pragma unroll
            for (int j = 0; j < TOPK; ++j) {
                out_idx_f[base + j] = (float)id[j];
                out_gate[base + j]  = ex[j] * inv;
            }
        }
    }
}

// ---------- refine: fp64 exact recompute, coalesced (validated) -------------
__global__ __launch_bounds__(256) void moe_gate_refine(
    const float* __restrict__ hs,
    const float* __restrict__ w,
    float* __restrict__ out_idx_f,
    float* __restrict__ out_gate,
    const int* __restrict__ flag_cnt,
    const int* __restrict__ flag_list,
    int flag_cap)
{
    __shared__ float  hrow[HID];
    __shared__ double lgw[4][NEXP];
    __shared__ double lgd[NEXP];
    const int tid  = threadIdx.x;
    const int lane = tid & 63;
    const int wv   = tid >> 6;

    int n = flag_cnt[0];
    if (n > flag_cap) n = flag_cap;

    for (int fi = blockIdx.x; fi < n; fi += gridDim.x) {
        const int t = flag_list[fi];
        #pragma unroll
        for (int i = 0; i < 4; ++i)
            ((f32x4*)hrow)[tid + 256 * i] =
                ((const f32x4*)(hs + (size_t)t * HID))[tid + 256 * i];
        __syncthreads();

        for (int e = 0; e < NEXP; ++e) {
            const f32x4* wp = (const f32x4*)(w + (size_t)e * HID);
            double s0 = 0.0, s1 = 0.0, s2 = 0.0, s3 = 0.0;
            #pragma unroll
            for (int i = 0; i < 4; ++i) {
                f32x4 wf = wp[tid + 256 * i];
                f32x4 af = ((const f32x4*)hrow)[tid + 256 * i];
                s0 = fma((double)wf[0], (double)af[0], s0);
                s1 = fma((double)wf[1], (double)af[1], s1);
                s2 = fma((double)wf[2], (double)af[2], s2);
                s3 = fma((double)wf[3], (double)af[3], s3);
            }
            double d = (s0 + s1) + (s2 + s3);
            #pragma unroll
            for (int off = 32; off > 0; off >>= 1)
                d += __shfl_down(d, off, 64);
            if (lane == 0) lgw[wv][e] = d;
        }
        __syncthreads();
        if (tid < NEXP)
            lgd[tid] = (lgw[0][tid] + lgw[1][tid]) + (lgw[2][tid] + lgw[3][tid]);
        __syncthreads();

        if (tid == 0) {
            double v[TOPK];
            int    id[TOPK];
            #pragma unroll
            for (int j = 0; j < TOPK; ++j) { v[j] = -INFINITY; id[j] = -1; }
            for (int e = 0; e < NEXP; ++e) {
                double x = lgd[e];
                if (x > v[TOPK - 1]) {
                    int p = TOPK - 1;
                    while (p > 0 && v[p - 1] < x) {
                        v[p]  = v[p - 1];
                        id[p] = id[p - 1];
                        --p;
                    }
                    v[p]  = x;
                    id[p] = e;
                }
            }
            double m = v[0];
            double ex[TOPK];
            double s = 0.0;
            #pragma unroll
            for (int j = 0; j < TOPK; ++j) { ex[j] = exp(v[j] - m); s += ex[j]; }
            double inv = 1.0 / s;
            size_t base = (size_t)t * TOPK;
            #pragma unroll
            for (int j = 0; j < TOPK; ++j) {
                out_idx_f[base + j] = (float)id[j];
                out_gate[base + j]  = (float)(ex[j] * inv);
            }
        }
        __syncthreads();
    }
}

extern "C" void kernel_launch(void* const* d_in, const int* in_sizes, int n_in,
                              void* d_out, int out_size, void* d_ws, size_t ws_size,
                              hipStream_t stream) {
    const float* hs = (const float*)d_in[0];
    const float* w  = (const float*)d_in[1];
    float* out      = (float*)d_out;
    float* out_idx  = out;
    float* out_gate = out + (size_t)TOKENS * TOPK;

    // ws: partials at front, flag region (64 KB) at the very end
    float* part     = (float*)d_ws;
    int*   flag_cnt = (int*)((char*)d_ws + (ws_size - FLAG_BYTES));
    int*   flag_list = flag_cnt + 1;
    int    flag_cap  = FLAG_BYTES / 4 - 2;

    // tokens per round limited by ws capacity for partials
    size_t avail = ws_size > FLAG_BYTES ? ws_size - FLAG_BYTES : 0;
    size_t rmax  = avail / ((size_t)KSPLIT * NEXP * 4);
    int R = (int)(rmax > (size_t)TOKENS ? (size_t)TOKENS : rmax);
    R &= ~(BT - 1);
    if (R < BT) R = BT;   // ws known >= 2MB from prior rounds; safe floor

    hipLaunchKernelGGL(zero_cnt_kernel, dim3(1), dim3(64), 0, stream, flag_cnt);

    for (int tok0 = 0; tok0 < TOKENS; tok0 += R) {
        int Rr = TOKENS - tok0 < R ? TOKENS - tok0 : R;
        hipLaunchKernelGGL(moe_gemm, dim3((Rr / BT) * KSPLIT), dim3(512), 0, stream,
                           hs, w, part, tok0, Rr);
        hipLaunchKernelGGL(moe_finish, dim3(Rr / 64), dim3(256), 0, stream,
                           part, out_idx, out_gate, flag_cnt, flag_list,
                           flag_cap, tok0, Rr);
    }

    hipLaunchKernelGGL(moe_gate_refine, dim3(REFINE_BLOCKS), dim3(256), 0, stream,
                       hs, w, out_idx, out_gate, flag_cnt, flag_list, flag_cap);
}